// Round 2
// baseline (289.275 us; speedup 1.0000x reference)
//
#include <hip/hip_runtime.h>
#include <type_traits>

typedef __attribute__((ext_vector_type(8))) short short8;
typedef __attribute__((ext_vector_type(4))) short short4v;
typedef __attribute__((ext_vector_type(4))) float f32x4;
typedef unsigned short u16;
typedef unsigned int u32;

#define N_CORES 64
#define N_QUBITS 1024
#define QEMB 256
#define N_EDGES 448
#define BATCH 512
#define THREADS 512

// workspace layout, in u16 elements (everything in ws is packed bf16)
#define WS_ADJA 0                   // 4096: adjacency, MFMA A-operand pack (for layer-3 agg)
#define WS_ADJB 4096                // 4096: adjacency^T, MFMA B-operand pack (for layer-1/2 agg)
#define WS_W1   8192                // 256x512 = 131072
#define WS_W2   (8192 + 131072)     // 139264: 512x512 = 262144
#define WS_W3   (139264 + 262144)   // 401408: 512x256 = 131072
#define WS_FLAG 532480              // 2 u16 = one u32 flag: 1 = inputs are f32, 0 = bf16

__device__ __forceinline__ float bf2f(u16 v) {
    u32 u = ((u32)v) << 16;
    return __builtin_bit_cast(float, u);
}
__device__ __forceinline__ u16 f2bf(float f) {
    u32 u = __builtin_bit_cast(u32, f);
    u32 r = u + 0x7FFFu + ((u >> 16) & 1u);   // RNE
    return (u16)(r >> 16);
}
// order-preserving float->uint key for atomicMax-based float max
__device__ __forceinline__ u32 fkey(float f) {
    u32 u = __builtin_bit_cast(u32, f);
    return u ^ (0x80000000u | (u32)((int)u >> 31));
}
__device__ __forceinline__ float keyf(u32 k) {
    u32 u = (k & 0x80000000u) ? (k ^ 0x80000000u) : ~k;
    return __builtin_bit_cast(float, u);
}
#define KEY_NEG_FLTMAX 0x00800000u   // fkey(-FLT_MAX)

// generic float loader: idx-th element of a buffer that is f32 (flag=1) or bf16
__device__ __forceinline__ float ldf(const void* p, int idx, u32 isf32) {
    return isf32 ? ((const float*)p)[idx] : bf2f(((const u16*)p)[idx]);
}

// ---------------------------------------------------------------------------
// Kernel -1: detect whether float inputs are f32 or bf16.
// Even-indexed u16s of a real bf16 buffer are genuine bf16 values of ~N(0,1)
// (exponent field in [100,134] essentially always). For an f32 buffer the
// even u16s are low mantissa halves: uniform bits, ~14% land in that window.
// ---------------------------------------------------------------------------
__global__ __launch_bounds__(64) void detect_dtype(const u16* __restrict__ q,
                                                   u32* __restrict__ flag) {
    __shared__ int cnt[64];
    int c = 0;
    for (int i = threadIdx.x; i < 2048; i += 64) {
        u16 v = q[i * 2];
        u32 e = (v >> 7) & 0xFF;
        c += (e >= 100 && e <= 134) ? 1 : 0;
    }
    cnt[threadIdx.x] = c;
    __syncthreads();
    if (threadIdx.x == 0) {
        int s = 0;
        for (int i = 0; i < 64; i++) s += cnt[i];
        *flag = (s < 1024) ? 1u : 0u;
    }
}

// ---------------------------------------------------------------------------
// Kernel 0a: build dense normalized adjacency (PyG gcn_norm w/ self loops),
// emit both MFMA operand packings to workspace. One block, 64 threads.
// ---------------------------------------------------------------------------
__global__ __launch_bounds__(64) void build_adj(const int* __restrict__ eidx,
                                                const void* __restrict__ ew,
                                                u16* __restrict__ ws) {
    __shared__ float A[N_CORES * N_CORES];
    __shared__ float dinv[N_CORES];
    __shared__ int er[N_EDGES];
    __shared__ int ec[N_EDGES];
    __shared__ float ewf[N_EDGES];
    const int t = threadIdx.x;   // 0..63
    const u32 isf32 = *(const u32*)(ws + WS_FLAG);

    for (int i = t; i < N_EDGES; i += 64) {
        er[i] = eidx[i];
        ec[i] = eidx[N_EDGES + i];
        ewf[i] = ldf(ew, i, isf32);
    }
    for (int i = t; i < N_CORES * N_CORES; i += 64) A[i] = 0.f;
    __syncthreads();

    // deg at target(col), incl. self-loop weight 1
    float dg = 1.0f;
    for (int e = 0; e < N_EDGES; e++)
        if (ec[e] == t) dg += ewf[e];
    dinv[t] = 1.0f / sqrtf(dg);
    __syncthreads();

    // scatter norm into dense A[col][row] (duplicates accumulate, like .at[].add)
    for (int e = t; e < N_EDGES; e += 64) {
        float nrm = dinv[er[e]] * ewf[e] * dinv[ec[e]];
        atomicAdd(&A[ec[e] * N_CORES + er[e]], nrm);
    }
    __syncthreads();
    A[t * N_CORES + t] += dinv[t] * dinv[t];   // self loop, weight 1
    __syncthreads();

    // Pack A as MFMA A-operand: elem (k>>3)*512 + m*8 + (k&7) = A[m][k]
    for (int i = t; i < 4096; i += 64) {
        int chunk = i >> 9, m = (i >> 3) & 63, j = i & 7;
        int k = chunk * 8 + j;
        ws[WS_ADJA + i] = f2bf(A[m * N_CORES + k]);
    }
    // Pack A^T as MFMA B-operand: chunk = ntc*2+kk; lane l, j:
    // value = A^T[k][c] = A[c][k], k = kk*32+(l>>4)*8+j, c = ntc*16+(l&15)
    for (int i = t; i < 4096; i += 64) {
        int chunk = i >> 9, l = (i >> 3) & 63, j = i & 7;
        int ntc = chunk >> 1, kk = chunk & 1;
        int k = kk * 32 + (l >> 4) * 8 + j;
        int c = ntc * 16 + (l & 15);
        ws[WS_ADJB + i] = f2bf(A[c * N_CORES + k]);
    }
}

// ---------------------------------------------------------------------------
// Kernel 0b: repack W1/W2/W3 into MFMA B-operand chunks (1 KB per chunk:
// 64 lanes x 16B, element (k = kk*32+(l>>4)*8+j, n = nt*16+(l&15))).
// One chunk per 64-thread block; 1024 blocks total.
// ---------------------------------------------------------------------------
__global__ __launch_bounds__(64) void pack_w(const void* __restrict__ W1,
                                             const void* __restrict__ W2,
                                             const void* __restrict__ W3,
                                             u16* __restrict__ ws) {
    const int b = blockIdx.x;
    const int l = threadIdx.x;
    const u32 isf32 = *(const u32*)(ws + WS_FLAG);
    const void* src;
    int N, K32, dst, nt, kk;
    if (b < 256)      { src = W1; N = 512; K32 = 8;  dst = WS_W1; nt = b / 8;          kk = b % 8; }
    else if (b < 768) { src = W2; N = 512; K32 = 16; dst = WS_W2; nt = (b - 256) / 16; kk = (b - 256) % 16; }
    else              { src = W3; N = 256; K32 = 16; dst = WS_W3; nt = (b - 768) / 16; kk = (b - 768) % 16; }
    const int col = nt * 16 + (l & 15);
    const int krow = kk * 32 + (l >> 4) * 8;
    u16 v[8];
#pragma unroll
    for (int j = 0; j < 8; j++) v[j] = f2bf(ldf(src, (krow + j) * N + col, isf32));
    u16* o = ws + dst + (nt * K32 + kk) * 512 + l * 8;
#pragma unroll
    for (int j = 0; j < 8; j++) o[j] = v[j];
}

// ---------------------------------------------------------------------------
// Fused per-batch kernel: pooling + 3 GCN layers entirely in LDS.
// One block = one batch element. 512 threads = 8 waves.
// ---------------------------------------------------------------------------
__global__ __launch_bounds__(THREADS) void fused_gcn(
    const int* __restrict__ allocs, const void* __restrict__ qembs,
    const void* __restrict__ dummy, const u16* __restrict__ ws,
    const void* __restrict__ b1g, const void* __restrict__ b2g,
    const void* __restrict__ b3g, void* __restrict__ out) {

    __shared__ __align__(16) u16 H[32768];     // 64KB: h, A-operand pack (K up to 512)
    __shared__ __align__(16) u16 HW[32768];    // 64KB: hw^T A-pack (L1/L2) or hw B-pack (L3); pooling keys
    __shared__ __align__(16) u16 ADJA[4096];   // 8KB
    __shared__ __align__(16) u16 ADJB[4096];   // 8KB
    __shared__ float BIAS[1280];               // 5KB: b1@0, b2@512, b3@1024
    __shared__ int ALLOC[1024];                // 4KB

    const int t = threadIdx.x;
    const int bb = blockIdx.x;
    const int wave = t >> 6, lane = t & 63, quad = lane >> 4, nl = lane & 15;
    const u32 isf32 = *(const u32*)(ws + WS_FLAG);

    // ---- stage constants + init pooling keys ----
    ALLOC[t] = allocs[bb * 1024 + t];
    ALLOC[512 + t] = allocs[bb * 1024 + 512 + t];
    ((uint4*)ADJA)[t] = ((const uint4*)(ws + WS_ADJA))[t];
    ((uint4*)ADJB)[t] = ((const uint4*)(ws + WS_ADJB))[t];
    BIAS[t] = ldf(b1g, t, isf32);
    BIAS[512 + t] = ldf(b2g, t, isf32);
    if (t < 256) BIAS[1024 + t] = ldf(b3g, t, isf32);
    u32* KEY = (u32*)HW;
#pragma unroll
    for (int i = 0; i < 32; i++) KEY[i * 512 + t] = KEY_NEG_FLTMAX;
    __syncthreads();

    // ---- pooling: per-core segment-max via LDS atomicMax on mapped keys ----
    {
        const int d = t & 255;
        const int qbase = (t >> 8) * 512;
        if (isf32) {
            const float* qe = (const float*)qembs + d;
            for (int it = 0; it < 512; it += 4) {
                const int q0 = qbase + it;
                float e0 = qe[(q0 + 0) * 256], e1 = qe[(q0 + 1) * 256];
                float e2 = qe[(q0 + 2) * 256], e3 = qe[(q0 + 3) * 256];
                int c0 = ALLOC[q0], c1 = ALLOC[q0 + 1], c2 = ALLOC[q0 + 2], c3 = ALLOC[q0 + 3];
                atomicMax(&KEY[c0 * 256 + d], fkey(e0));
                atomicMax(&KEY[c1 * 256 + d], fkey(e1));
                atomicMax(&KEY[c2 * 256 + d], fkey(e2));
                atomicMax(&KEY[c3 * 256 + d], fkey(e3));
            }
        } else {
            const u16* qe = (const u16*)qembs + d;
            for (int it = 0; it < 512; it += 4) {
                const int q0 = qbase + it;
                u16 e0 = qe[(q0 + 0) * 256], e1 = qe[(q0 + 1) * 256];
                u16 e2 = qe[(q0 + 2) * 256], e3 = qe[(q0 + 3) * 256];
                int c0 = ALLOC[q0], c1 = ALLOC[q0 + 1], c2 = ALLOC[q0 + 2], c3 = ALLOC[q0 + 3];
                atomicMax(&KEY[c0 * 256 + d], fkey(bf2f(e0)));
                atomicMax(&KEY[c1 * 256 + d], fkey(bf2f(e1)));
                atomicMax(&KEY[c2 * 256 + d], fkey(bf2f(e2)));
                atomicMax(&KEY[c3 * 256 + d], fkey(bf2f(e3)));
            }
        }
    }
    __syncthreads();

    // ---- combine with dummy emb, pack x into H as A-operand (m=core, k=dim) ----
    {
        const int d = t & 255;
        const float dum = ldf(dummy, d, isf32);
#pragma unroll 4
        for (int i = 0; i < 32; i++) {
            const int c = i * 2 + (t >> 8);
            float f = fmaxf(keyf(KEY[c * 256 + d]), dum);
            H[(d >> 3) * 512 + c * 8 + (d & 7)] = f2bf(f);
        }
    }
    __syncthreads();

    // ================= layer macro bodies =================
    // mm1: C[64,N] = h[64,K] @ W[K,N]; A from H (A-pack), B streamed from
    // packed global weights. Epilogue:
    //   WRITE_B=false: store C^T into HW as A-operand pack (rows=n, k=m) [L1/L2]
    //   WRITE_B=true : store C into HW as B-operand pack (k=m, col=n)    [L3]
    auto mm1 = [&](auto K32c, auto Nc, auto WRITEBc, const u16* __restrict__ W) {
        constexpr int K32 = decltype(K32c)::value;
        constexpr int N = decltype(Nc)::value;
        constexpr bool WRITE_B = decltype(WRITEBc)::value;
        constexpr int NT = N / 16;
        const int rt = wave & 3;
        const int nt0 = (wave >> 2) * (NT / 2);
        short8 a[K32];
#pragma unroll
        for (int kk = 0; kk < K32; kk++)
            a[kk] = *(const short8*)(H + (kk * 4 + quad) * 512 + (rt * 16 + nl) * 8);
#pragma unroll
        for (int ni = 0; ni < NT / 2; ni += 2) {
            const int ntA = nt0 + ni, ntB = ntA + 1;
            f32x4 acc0 = {0.f, 0.f, 0.f, 0.f}, acc1 = {0.f, 0.f, 0.f, 0.f};
#pragma unroll
            for (int kk = 0; kk < K32; kk++) {
                short8 bA = *(const short8*)(W + (ntA * K32 + kk) * 512 + lane * 8);
                short8 bB = *(const short8*)(W + (ntB * K32 + kk) * 512 + lane * 8);
                acc0 = __builtin_amdgcn_mfma_f32_16x16x32_bf16(a[kk], bA, acc0, 0, 0, 0);
                acc1 = __builtin_amdgcn_mfma_f32_16x16x32_bf16(a[kk], bB, acc1, 0, 0, 0);
            }
#pragma unroll
            for (int s = 0; s < 2; s++) {
                const int nt = s ? ntB : ntA;
                f32x4 acc = s ? acc1 : acc0;
                short4v p;
#pragma unroll
                for (int rr = 0; rr < 4; rr++) p[rr] = (short)f2bf(acc[rr]);
                if (WRITE_B) {
                    const int kk2 = rt >> 1;
                    const int q2 = (rt * 2 + (quad >> 1)) & 3;
                    *(short4v*)(HW + (nt * 2 + kk2) * 512 + (q2 * 16 + nl) * 8 + (quad & 1) * 4) = p;
                } else {
                    const int kkr = rt >> 1;
                    const int qr = (rt * 2 + (quad >> 1)) & 3;
                    const int n = nt * 16 + nl;
                    *(short4v*)(HW + (kkr * 4 + qr) * 4096 + n * 8 + (quad & 1) * 4) = p;
                }
            }
        }
    };

    // mm2T (L1/L2): agg^T[n][c] = sum_r hw^T[n][r] * A^T[r][c]; A-op = HW (M=512),
    // B-op = ADJB. relu+bias, store h_next into H as A-pack (m=c, k=n).
    auto mm2T = [&](const float* __restrict__ bias) {
        short8 bf[2][4];
#pragma unroll
        for (int kk = 0; kk < 2; kk++)
#pragma unroll
            for (int ntc = 0; ntc < 4; ntc++)
                bf[kk][ntc] = *(const short8*)(ADJB + (ntc * 2 + kk) * 512 + lane * 8);
#pragma unroll
        for (int i = 0; i < 4; i++) {
            const int rtp = wave * 4 + i;
            short8 a0 = *(const short8*)(HW + (0 + quad) * 4096 + (rtp * 16 + nl) * 8);
            short8 a1 = *(const short8*)(HW + (4 + quad) * 4096 + (rtp * 16 + nl) * 8);
            float bv[4];
#pragma unroll
            for (int rr = 0; rr < 4; rr++) bv[rr] = bias[rtp * 16 + quad * 4 + rr];
#pragma unroll
            for (int ntc = 0; ntc < 4; ntc++) {
                f32x4 acc = {0.f, 0.f, 0.f, 0.f};
                acc = __builtin_amdgcn_mfma_f32_16x16x32_bf16(a0, bf[0][ntc], acc, 0, 0, 0);
                acc = __builtin_amdgcn_mfma_f32_16x16x32_bf16(a1, bf[1][ntc], acc, 0, 0, 0);
                const int c = ntc * 16 + nl;
                short4v p;
#pragma unroll
                for (int rr = 0; rr < 4; rr++)
                    p[rr] = (short)f2bf(fmaxf(acc[rr] + bv[rr], 0.f));
                const int chunkid = rtp * 2 + (quad >> 1);
                *(short4v*)(H + chunkid * 512 + c * 8 + (quad & 1) * 4) = p;
            }
        }
    };

    // mm2 L3: agg[m][n] = sum_r A[m][r] * hw[r][n]; A-op = ADJA, B-op = HW
    // (B-pack). relu+bias, store straight to global out (dtype per flag).
    auto mm2L3 = [&](const float* __restrict__ bias) {
        const int rt2 = wave & 3;
        const int nt0 = (wave >> 2) * 8;
        short8 a0 = *(const short8*)(ADJA + (0 + quad) * 512 + (rt2 * 16 + nl) * 8);
        short8 a1 = *(const short8*)(ADJA + (4 + quad) * 512 + (rt2 * 16 + nl) * 8);
        float* outf = (float*)out + (size_t)bb * 64 * 256;
        u16* outu = (u16*)out + (size_t)bb * 64 * 256;
#pragma unroll
        for (int ni = 0; ni < 8; ni++) {
            const int nt = nt0 + ni;
            short8 b0 = *(const short8*)(HW + (nt * 2 + 0) * 512 + lane * 8);
            short8 b1 = *(const short8*)(HW + (nt * 2 + 1) * 512 + lane * 8);
            f32x4 acc = {0.f, 0.f, 0.f, 0.f};
            acc = __builtin_amdgcn_mfma_f32_16x16x32_bf16(a0, b0, acc, 0, 0, 0);
            acc = __builtin_amdgcn_mfma_f32_16x16x32_bf16(a1, b1, acc, 0, 0, 0);
            const int n = nt * 16 + nl;
            const float bv = bias[n];
#pragma unroll
            for (int rr = 0; rr < 4; rr++) {
                const int m2 = rt2 * 16 + quad * 4 + rr;
                float val = fmaxf(acc[rr] + bv, 0.f);
                if (isf32) outf[m2 * 256 + n] = val;
                else       outu[m2 * 256 + n] = f2bf(val);
            }
        }
    };

    // ================= layers =================
    mm1(std::integral_constant<int, 8>{},  std::integral_constant<int, 512>{},
        std::integral_constant<bool, false>{}, ws + WS_W1);
    __syncthreads();
    mm2T(BIAS + 0);
    __syncthreads();

    mm1(std::integral_constant<int, 16>{}, std::integral_constant<int, 512>{},
        std::integral_constant<bool, false>{}, ws + WS_W2);
    __syncthreads();
    mm2T(BIAS + 512);
    __syncthreads();

    mm1(std::integral_constant<int, 16>{}, std::integral_constant<int, 256>{},
        std::integral_constant<bool, true>{}, ws + WS_W3);
    __syncthreads();
    mm2L3(BIAS + 1024);
}

// ---------------------------------------------------------------------------
extern "C" void kernel_launch(void* const* d_in, const int* in_sizes, int n_in,
                              void* d_out, int out_size, void* d_ws, size_t ws_size,
                              hipStream_t stream) {
    const int* allocs = (const int*)d_in[0];
    const void* qembs = d_in[1];
    const void* dummy = d_in[2];
    const int* eidx   = (const int*)d_in[3];
    const void* ew    = d_in[4];
    const void* W1 = d_in[5];
    const void* b1 = d_in[6];
    const void* W2 = d_in[7];
    const void* b2 = d_in[8];
    const void* W3 = d_in[9];
    const void* b3 = d_in[10];
    u16* ws = (u16*)d_ws;

    detect_dtype<<<1, 64, 0, stream>>>((const u16*)qembs, (u32*)(ws + WS_FLAG));
    build_adj<<<1, 64, 0, stream>>>(eidx, ew, ws);
    pack_w<<<1024, 64, 0, stream>>>(W1, W2, W3, ws);
    fused_gcn<<<BATCH, THREADS, 0, stream>>>(allocs, qembs, dummy, ws, b1, b2, b3, d_out);
}

// Round 3
// 226.232 us; speedup vs baseline: 1.2787x; 1.2787x over previous
//
#include <hip/hip_runtime.h>
#include <type_traits>

typedef __attribute__((ext_vector_type(8))) short short8;
typedef __attribute__((ext_vector_type(4))) short short4v;
typedef __attribute__((ext_vector_type(4))) float f32x4;
typedef unsigned short u16;
typedef unsigned int u32;

#define N_EDGES 448

// ws layout (u16 units); everything in ws is bf16 (or raw int/flag)
#define WS_ADJA 0                    // 4096: A_norm, MFMA A-operand pack
#define WS_ADJB 4096                 // 4096: A_norm^T, MFMA B-operand pack
#define WS_W1   8192                 // 256x512
#define WS_W2   139264               // 512x512
#define WS_W3   401408               // 512x256
#define WS_DUM  532480               // dummy 256 | b1 512 | b2 512 | b3 256
#define WS_B1   (WS_DUM + 256)
#define WS_B2   (WS_DUM + 768)
#define WS_B3   (WS_DUM + 1280)
#define WS_FLAG 534016               // u32: 1 = f32 inputs, 0 = bf16
#define WS_X    534024               // 512 * 16384: pooled X, A-pack per batch elem
#define WS_END_A (WS_X + 512 * 16384)

__device__ __forceinline__ float bf2f(u16 v) {
    u32 u = ((u32)v) << 16;
    return __builtin_bit_cast(float, u);
}
__device__ __forceinline__ u16 f2bf(float f) {
    u32 u = __builtin_bit_cast(u32, f);
    u32 r = u + 0x7FFFu + ((u >> 16) & 1u);   // RNE
    return (u16)(r >> 16);
}
__device__ __forceinline__ u32 fkey(float f) {
    u32 u = __builtin_bit_cast(u32, f);
    return u ^ (0x80000000u | (u32)((int)u >> 31));
}
__device__ __forceinline__ float keyf(u32 k) {
    u32 u = (k & 0x80000000u) ? (k ^ 0x80000000u) : ~k;
    return __builtin_bit_cast(float, u);
}
#define KEY_NEG_FLTMAX 0x00800000u

__device__ __forceinline__ float ldf(const void* p, int idx, u32 isf32) {
    return isf32 ? ((const float*)p)[idx] : bf2f(((const u16*)p)[idx]);
}

// ---------------------------------------------------------------------------
// prep: one kernel, 1026 blocks x 64 threads.
//   block 0:      dense gcn_norm adjacency -> ADJA (A-pack) + ADJB (B-pack) + flag
//   1..1024:      pack W1/W2/W3 into MFMA B-operand 1KB chunks
//   1025:         dummy + b1 + b2 + b3 -> bf16 in ws
// Each block detects input dtype locally (256-sample exponent histogram).
// ---------------------------------------------------------------------------
__global__ __launch_bounds__(64) void prep(
    const int* __restrict__ eidx, const void* __restrict__ ew,
    const void* __restrict__ qembs, const void* __restrict__ dummy,
    const void* __restrict__ W1, const void* __restrict__ b1,
    const void* __restrict__ W2, const void* __restrict__ b2,
    const void* __restrict__ W3, const void* __restrict__ b3,
    u16* __restrict__ ws) {
    const int t = threadIdx.x;
    // local dtype detect
    int cdet = 0;
    const u16* qs = (const u16*)qembs;
#pragma unroll
    for (int j = 0; j < 4; j++) {
        u16 v = qs[(t * 4 + j) * 2];
        u32 e = (v >> 7) & 0xFF;
        cdet += (e >= 100 && e <= 134) ? 1 : 0;
    }
#pragma unroll
    for (int off = 32; off > 0; off >>= 1) cdet += __shfl_down(cdet, off, 64);
    cdet = __shfl(cdet, 0, 64);
    const u32 isf32 = (cdet < 128) ? 1u : 0u;

    const int b = blockIdx.x;
    if (b == 0) {
        __shared__ float A[64 * 64];
        __shared__ float dinv[64];
        __shared__ int er[N_EDGES];
        __shared__ int ec[N_EDGES];
        __shared__ float ewf[N_EDGES];
        for (int i = t; i < N_EDGES; i += 64) {
            er[i] = eidx[i];
            ec[i] = eidx[N_EDGES + i];
            ewf[i] = ldf(ew, i, isf32);
        }
        for (int i = t; i < 64 * 64; i += 64) A[i] = 0.f;
        __syncthreads();
        float dg = 1.0f;
        for (int e = 0; e < N_EDGES; e++)
            if (ec[e] == t) dg += ewf[e];
        dinv[t] = 1.0f / sqrtf(dg);
        __syncthreads();
        for (int e = t; e < N_EDGES; e += 64) {
            float nrm = dinv[er[e]] * ewf[e] * dinv[ec[e]];
            atomicAdd(&A[ec[e] * 64 + er[e]], nrm);
        }
        __syncthreads();
        A[t * 64 + t] += dinv[t] * dinv[t];
        __syncthreads();
        // A-pack: elem (k>>3)*512 + m*8 + (k&7) = A[m][k]
        for (int i = t; i < 4096; i += 64) {
            int chunk = i >> 9, m = (i >> 3) & 63, j = i & 7;
            ws[WS_ADJA + i] = f2bf(A[m * 64 + chunk * 8 + j]);
        }
        // B-pack of A^T: chunk = ntc*2+kk: lane l, j: A[c][k], k=kk*32+(l>>4)*8+j, c=ntc*16+(l&15)
        for (int i = t; i < 4096; i += 64) {
            int chunk = i >> 9, l = (i >> 3) & 63, j = i & 7;
            int ntc = chunk >> 1, kk = chunk & 1;
            int k = kk * 32 + (l >> 4) * 8 + j;
            int c = ntc * 16 + (l & 15);
            ws[WS_ADJB + i] = f2bf(A[c * 64 + k]);
        }
        if (t == 0) *(u32*)(ws + WS_FLAG) = isf32;
    } else if (b <= 1024) {
        const int bw = b - 1;
        const void* src;
        int N, K32, dst, nt, kk;
        if (bw < 256)      { src = W1; N = 512; K32 = 8;  dst = WS_W1; nt = bw / 8;          kk = bw % 8; }
        else if (bw < 768) { src = W2; N = 512; K32 = 16; dst = WS_W2; nt = (bw - 256) / 16; kk = (bw - 256) % 16; }
        else               { src = W3; N = 256; K32 = 16; dst = WS_W3; nt = (bw - 768) / 16; kk = (bw - 768) % 16; }
        const int col = nt * 16 + (t & 15);
        const int krow = kk * 32 + (t >> 4) * 8;
        u16 v[8];
#pragma unroll
        for (int j = 0; j < 8; j++) v[j] = f2bf(ldf(src, (krow + j) * N + col, isf32));
        u16* o = ws + dst + (nt * K32 + kk) * 512 + t * 8;
#pragma unroll
        for (int j = 0; j < 8; j++) o[j] = v[j];
    } else {
        for (int j = 0; j < 24; j++) {
            int i = t + j * 64;
            float v;
            if (i < 256)       v = ldf(dummy, i, isf32);
            else if (i < 768)  v = ldf(b1, i - 256, isf32);
            else if (i < 1280) v = ldf(b2, i - 768, isf32);
            else               v = ldf(b3, i - 1280, isf32);
            ws[WS_DUM + i] = f2bf(v);
        }
    }
}

// ---------------------------------------------------------------------------
// pool: one block per batch elem (512 x 512). LDS 68KB -> 2 blocks/CU.
// Segment-max via LDS atomicMax on order-preserving keys; writes X A-pack to ws.
// ---------------------------------------------------------------------------
__global__ __launch_bounds__(512) void pool(const int* __restrict__ allocs,
                                            const void* __restrict__ qembs,
                                            u16* __restrict__ ws) {
    __shared__ u32 KEY[16384];   // 64KB: [core][dim]
    __shared__ int AL[1024];
    const int t = threadIdx.x, bb = blockIdx.x;
    const u32 isf32 = *(const u32*)(ws + WS_FLAG);
    AL[t] = allocs[bb * 1024 + t];
    AL[512 + t] = allocs[bb * 1024 + 512 + t];
#pragma unroll
    for (int i = 0; i < 32; i++) KEY[i * 512 + t] = KEY_NEG_FLTMAX;
    __syncthreads();
    const int d = t & 255;
    const int qbase = (t >> 8) * 512;
    if (isf32) {
        const float* qe = (const float*)qembs + d;
        for (int it = 0; it < 512; it += 4) {
            const int q0 = qbase + it;
            float e0 = qe[(q0 + 0) * 256], e1 = qe[(q0 + 1) * 256];
            float e2 = qe[(q0 + 2) * 256], e3 = qe[(q0 + 3) * 256];
            int c0 = AL[q0], c1 = AL[q0 + 1], c2 = AL[q0 + 2], c3 = AL[q0 + 3];
            atomicMax(&KEY[c0 * 256 + d], fkey(e0));
            atomicMax(&KEY[c1 * 256 + d], fkey(e1));
            atomicMax(&KEY[c2 * 256 + d], fkey(e2));
            atomicMax(&KEY[c3 * 256 + d], fkey(e3));
        }
    } else {
        const u16* qe = (const u16*)qembs + d;
        for (int it = 0; it < 512; it += 4) {
            const int q0 = qbase + it;
            u16 e0 = qe[(q0 + 0) * 256], e1 = qe[(q0 + 1) * 256];
            u16 e2 = qe[(q0 + 2) * 256], e3 = qe[(q0 + 3) * 256];
            int c0 = AL[q0], c1 = AL[q0 + 1], c2 = AL[q0 + 2], c3 = AL[q0 + 3];
            atomicMax(&KEY[c0 * 256 + d], fkey(bf2f(e0)));
            atomicMax(&KEY[c1 * 256 + d], fkey(bf2f(e1)));
            atomicMax(&KEY[c2 * 256 + d], fkey(bf2f(e2)));
            atomicMax(&KEY[c3 * 256 + d], fkey(bf2f(e3)));
        }
    }
    __syncthreads();
    const float dum = bf2f(ws[WS_DUM + d]);
    u16* X = ws + WS_X + bb * 16384;
#pragma unroll 4
    for (int i = 0; i < 32; i++) {
        const int cc = i * 2 + (t >> 8);
        float f = fmaxf(keyf(KEY[cc * 256 + d]), dum);
        X[(d >> 3) * 512 + cc * 8 + (d & 7)] = f2bf(f);
    }
}

// ---------------------------------------------------------------------------
// fused: stripe-structured 3-layer GCN, one block per batch elem (512 thr).
// Each wave owns disjoint 16-col stripes: mm1 K-loop (B chunks read once per
// block) -> per-wave LDS-scratch transpose -> agg MFMA vs ADJB -> bias/relu
// -> next A-pack. LDS 141KB (HA+HB ping-pong + per-wave scratch).
// ---------------------------------------------------------------------------
template <bool POOL>
__global__ __launch_bounds__(512, 2) void fused(
    const int* __restrict__ allocs, const void* __restrict__ qembs,
    const u16* __restrict__ wsr, void* __restrict__ out) {

    __shared__ __align__(16) u16 HA[32768];
    __shared__ __align__(16) u16 HB[32768];
    __shared__ __align__(16) u16 SCR[8 * 640];   // per-wave transpose scratch (stride-40 rows)

    const int t = threadIdx.x, bb = blockIdx.x;
    const int wave = t >> 6, lane = t & 63, quad = lane >> 4, nl = lane & 15;
    const u32 isf32 = *(const u32*)(wsr + WS_FLAG);

    if (POOL) {
        int* AL = (int*)SCR;
        AL[t] = allocs[bb * 1024 + t];
        AL[512 + t] = allocs[bb * 1024 + 512 + t];
        u32* KEY = (u32*)HA;
#pragma unroll
        for (int i = 0; i < 32; i++) KEY[i * 512 + t] = KEY_NEG_FLTMAX;
        __syncthreads();
        const int d = t & 255;
        const int qbase = (t >> 8) * 512;
        if (isf32) {
            const float* qe = (const float*)qembs + d;
            for (int it = 0; it < 512; it += 4) {
                const int q0 = qbase + it;
                float e0 = qe[(q0 + 0) * 256], e1 = qe[(q0 + 1) * 256];
                float e2 = qe[(q0 + 2) * 256], e3 = qe[(q0 + 3) * 256];
                int c0 = AL[q0], c1 = AL[q0 + 1], c2 = AL[q0 + 2], c3 = AL[q0 + 3];
                atomicMax(&KEY[c0 * 256 + d], fkey(e0));
                atomicMax(&KEY[c1 * 256 + d], fkey(e1));
                atomicMax(&KEY[c2 * 256 + d], fkey(e2));
                atomicMax(&KEY[c3 * 256 + d], fkey(e3));
            }
        } else {
            const u16* qe = (const u16*)qembs + d;
            for (int it = 0; it < 512; it += 4) {
                const int q0 = qbase + it;
                u16 e0 = qe[(q0 + 0) * 256], e1 = qe[(q0 + 1) * 256];
                u16 e2 = qe[(q0 + 2) * 256], e3 = qe[(q0 + 3) * 256];
                int c0 = AL[q0], c1 = AL[q0 + 1], c2 = AL[q0 + 2], c3 = AL[q0 + 3];
                atomicMax(&KEY[c0 * 256 + d], fkey(bf2f(e0)));
                atomicMax(&KEY[c1 * 256 + d], fkey(bf2f(e1)));
                atomicMax(&KEY[c2 * 256 + d], fkey(bf2f(e2)));
                atomicMax(&KEY[c3 * 256 + d], fkey(bf2f(e3)));
            }
        }
        __syncthreads();
        const float dum = bf2f(wsr[WS_DUM + d]);
#pragma unroll 4
        for (int i = 0; i < 32; i++) {
            const int cc = i * 2 + (t >> 8);
            float f = fmaxf(keyf(KEY[cc * 256 + d]), dum);
            HB[(d >> 3) * 512 + cc * 8 + (d & 7)] = f2bf(f);
        }
        __syncthreads();
    } else {
        const uint4* src = (const uint4*)(wsr + WS_X + bb * 16384);
        uint4* dst = (uint4*)HB;
#pragma unroll
        for (int i = 0; i < 4; i++) dst[i * 512 + t] = src[i * 512 + t];
        __syncthreads();
    }

    // preload A_norm^T B-operand frags (k-chunk h, col-tile ntc)
    short8 adjB[4][2];
#pragma unroll
    for (int ntc = 0; ntc < 4; ntc++)
#pragma unroll
        for (int h = 0; h < 2; h++)
            adjB[ntc][h] = *(const short8*)(wsr + WS_ADJB + (ntc * 2 + h) * 512 + lane * 8);

    u16* scr = SCR + wave * 640;

    // mm1 + fused agg for L1/L2. Wave owns stripes nt = wave*4 .. +3.
    auto layerT = [&](auto K32c, const u16* __restrict__ W, const u16* __restrict__ bias,
                      const u16* __restrict__ Hin, u16* __restrict__ Hout) {
        constexpr int K32 = decltype(K32c)::value;
        const int s0 = wave * 4;
        f32x4 acc[4][4];   // [stripe][row-tile]
#pragma unroll
        for (int s = 0; s < 4; s++)
#pragma unroll
            for (int rt = 0; rt < 4; rt++) acc[s][rt] = f32x4{0.f, 0.f, 0.f, 0.f};
#pragma unroll
        for (int kk = 0; kk < K32; kk++) {
            short8 a[4], bch[4];
#pragma unroll
            for (int rt = 0; rt < 4; rt++)
                a[rt] = *(const short8*)(Hin + (kk * 4 + quad) * 512 + (rt * 16 + nl) * 8);
#pragma unroll
            for (int s = 0; s < 4; s++)
                bch[s] = *(const short8*)(W + ((s0 + s) * K32 + kk) * 512 + lane * 8);
#pragma unroll
            for (int s = 0; s < 4; s++)
#pragma unroll
                for (int rt = 0; rt < 4; rt++)
                    acc[s][rt] = __builtin_amdgcn_mfma_f32_16x16x32_bf16(a[rt], bch[s], acc[s][rt], 0, 0, 0);
        }
#pragma unroll
        for (int s = 0; s < 4; s++) {
            const int nt = s0 + s;
            f32x4 agg[4];
#pragma unroll
            for (int ntc = 0; ntc < 4; ntc++) agg[ntc] = f32x4{0.f, 0.f, 0.f, 0.f};
#pragma unroll
            for (int h = 0; h < 2; h++) {
                // transpose C-layout (core rows) -> k-major frag via per-wave scratch
#pragma unroll
                for (int r2 = 0; r2 < 2; r2++) {
                    f32x4 v = acc[s][2 * h + r2];
                    short4v p;
#pragma unroll
                    for (int rr = 0; rr < 4; rr++) p[rr] = (short)f2bf(v[rr]);
                    *(short4v*)(scr + nl * 40 + r2 * 16 + quad * 4) = p;
                }
                short8 hwf = *(const short8*)(scr + nl * 40 + quad * 8);
#pragma unroll
                for (int ntc = 0; ntc < 4; ntc++)
                    agg[ntc] = __builtin_amdgcn_mfma_f32_16x16x32_bf16(hwf, adjB[ntc][h], agg[ntc], 0, 0, 0);
            }
            float bv[4];
#pragma unroll
            for (int rr = 0; rr < 4; rr++) bv[rr] = bf2f(bias[nt * 16 + quad * 4 + rr]);
#pragma unroll
            for (int ntc = 0; ntc < 4; ntc++) {
                short4v p;
#pragma unroll
                for (int rr = 0; rr < 4; rr++)
                    p[rr] = (short)f2bf(fmaxf(agg[ntc][rr] + bv[rr], 0.f));
                *(short4v*)(Hout + (nt * 2 + (quad >> 1)) * 512 + (ntc * 16 + nl) * 8 + (quad & 1) * 4) = p;
            }
        }
    };

    // L3 mm1: hw3 = x3 @ W3 (N=256, 2 stripes/wave); deposit B-pack into HA.
    auto layer3 = [&](const u16* __restrict__ W) {
        const int s0 = wave * 2;
        f32x4 acc[2][4];
#pragma unroll
        for (int s = 0; s < 2; s++)
#pragma unroll
            for (int rt = 0; rt < 4; rt++) acc[s][rt] = f32x4{0.f, 0.f, 0.f, 0.f};
#pragma unroll
        for (int kk = 0; kk < 16; kk++) {
            short8 a[4], bch[2];
#pragma unroll
            for (int rt = 0; rt < 4; rt++)
                a[rt] = *(const short8*)(HB + (kk * 4 + quad) * 512 + (rt * 16 + nl) * 8);
#pragma unroll
            for (int s = 0; s < 2; s++)
                bch[s] = *(const short8*)(W + ((s0 + s) * 16 + kk) * 512 + lane * 8);
#pragma unroll
            for (int s = 0; s < 2; s++)
#pragma unroll
                for (int rt = 0; rt < 4; rt++)
                    acc[s][rt] = __builtin_amdgcn_mfma_f32_16x16x32_bf16(a[rt], bch[s], acc[s][rt], 0, 0, 0);
        }
#pragma unroll
        for (int s = 0; s < 2; s++) {
            const int nt = s0 + s;
#pragma unroll
            for (int h = 0; h < 2; h++) {
#pragma unroll
                for (int r2 = 0; r2 < 2; r2++) {
                    f32x4 v = acc[s][2 * h + r2];
                    short4v p;
#pragma unroll
                    for (int rr = 0; rr < 4; rr++) p[rr] = (short)f2bf(v[rr]);
                    *(short4v*)(scr + nl * 40 + r2 * 16 + quad * 4) = p;
                }
                short8 hwf = *(const short8*)(scr + nl * 40 + quad * 8);
                *(short8*)(HA + (nt * 2 + h) * 512 + lane * 8) = hwf;
            }
        }
    };

    // final: out = relu(A_norm @ hw3 + b3), coalesced f32 stores
    auto finalOut = [&]() {
        const int rt2 = wave & 3, nt0 = (wave >> 2) * 8;
        short8 aA[2];
#pragma unroll
        for (int h = 0; h < 2; h++)
            aA[h] = *(const short8*)(wsr + WS_ADJA + (h * 4 + quad) * 512 + (rt2 * 16 + nl) * 8);
        float* outf = (float*)out + (size_t)bb * 16384;
        u16* outu = (u16*)out + (size_t)bb * 16384;
#pragma unroll
        for (int ni = 0; ni < 8; ni++) {
            const int nt = nt0 + ni;
            short8 b0 = *(const short8*)(HA + (nt * 2 + 0) * 512 + lane * 8);
            short8 b1 = *(const short8*)(HA + (nt * 2 + 1) * 512 + lane * 8);
            f32x4 acc = f32x4{0.f, 0.f, 0.f, 0.f};
            acc = __builtin_amdgcn_mfma_f32_16x16x32_bf16(aA[0], b0, acc, 0, 0, 0);
            acc = __builtin_amdgcn_mfma_f32_16x16x32_bf16(aA[1], b1, acc, 0, 0, 0);
            const int n = nt * 16 + nl;
            const float bv = bf2f(wsr[WS_B3 + n]);
#pragma unroll
            for (int rr = 0; rr < 4; rr++) {
                const int m2 = rt2 * 16 + quad * 4 + rr;
                float val = fmaxf(acc[rr] + bv, 0.f);
                if (isf32) outf[m2 * 256 + n] = val;
                else       outu[m2 * 256 + n] = f2bf(val);
            }
        }
    };

    layerT(std::integral_constant<int, 8>{},  wsr + WS_W1, wsr + WS_B1, HB, HA);
    __syncthreads();
    layerT(std::integral_constant<int, 16>{}, wsr + WS_W2, wsr + WS_B2, HA, HB);
    __syncthreads();
    layer3(wsr + WS_W3);
    __syncthreads();
    finalOut();
}

// ---------------------------------------------------------------------------
extern "C" void kernel_launch(void* const* d_in, const int* in_sizes, int n_in,
                              void* d_out, int out_size, void* d_ws, size_t ws_size,
                              hipStream_t stream) {
    const int* allocs = (const int*)d_in[0];
    const void* qembs = d_in[1];
    const void* dummy = d_in[2];
    const int* eidx   = (const int*)d_in[3];
    const void* ew    = d_in[4];
    const void* W1 = d_in[5];
    const void* b1 = d_in[6];
    const void* W2 = d_in[7];
    const void* b2 = d_in[8];
    const void* W3 = d_in[9];
    const void* b3 = d_in[10];
    u16* ws = (u16*)d_ws;

    prep<<<1026, 64, 0, stream>>>(eidx, ew, qembs, dummy, W1, b1, W2, b2, W3, b3, ws);
    const bool bigws = ws_size >= (size_t)WS_END_A * 2;
    if (bigws) {
        pool<<<512, 512, 0, stream>>>(allocs, qembs, ws);
        fused<false><<<512, 512, 0, stream>>>(allocs, qembs, ws, d_out);
    } else {
        fused<true><<<512, 512, 0, stream>>>(allocs, qembs, ws, d_out);
    }
}

// Round 4
// 150.435 us; speedup vs baseline: 1.9229x; 1.5039x over previous
//
#include <hip/hip_runtime.h>
#include <type_traits>

typedef __attribute__((ext_vector_type(8))) short short8;
typedef __attribute__((ext_vector_type(4))) short short4v;
typedef __attribute__((ext_vector_type(4))) float f32x4;
typedef unsigned short u16;
typedef unsigned int u32;

#define N_EDGES 448

// ws layout (u16 units); everything in ws is bf16 (or raw flag)
#define WS_ADJA 0                    // 4096: A_norm, MFMA A-operand pack
#define WS_ADJB 4096                 // 4096: A_norm^T, MFMA B-operand pack
#define WS_W1   8192                 // 256x512
#define WS_W2   139264               // 512x512
#define WS_W3   401408               // 512x256
#define WS_DUM  532480               // dummy 256 | b1 512 | b2 512 | b3 256 (bf16)
#define WS_B1   (WS_DUM + 256)
#define WS_B2   (WS_DUM + 768)
#define WS_B3   (WS_DUM + 1280)
#define WS_FLAG 534272               // u32: 1 = f32 inputs, 0 = bf16

__device__ __forceinline__ float bf2f(u16 v) {
    u32 u = ((u32)v) << 16;
    return __builtin_bit_cast(float, u);
}
__device__ __forceinline__ u16 f2bf(float f) {
    u32 u = __builtin_bit_cast(u32, f);
    u32 r = u + 0x7FFFu + ((u >> 16) & 1u);   // RNE
    return (u16)(r >> 16);
}
__device__ __forceinline__ float ldf(const void* p, int idx, u32 isf32) {
    return isf32 ? ((const float*)p)[idx] : bf2f(((const u16*)p)[idx]);
}

// ---------------------------------------------------------------------------
// prep: 129 blocks x 512 threads.
//   block 0:   biases/dummy -> bf16 ws; dense gcn_norm adjacency -> ADJA/ADJB; flag
//   1..128:    pack W1/W2/W3 into MFMA B-operand 1KB chunks (8 chunks/block)
// ---------------------------------------------------------------------------
__global__ __launch_bounds__(512) void prep(
    const int* __restrict__ eidx, const void* __restrict__ ew,
    const void* __restrict__ qembs, const void* __restrict__ dummy,
    const void* __restrict__ W1, const void* __restrict__ b1,
    const void* __restrict__ W2, const void* __restrict__ b2,
    const void* __restrict__ W3, const void* __restrict__ b3,
    u16* __restrict__ ws) {
    const int t = threadIdx.x, b = blockIdx.x;
    __shared__ u32 s_isf;
    // local dtype detect (wave 0)
    if (t < 64) {
        const u16* qs = (const u16*)qembs;
        int c = 0;
#pragma unroll
        for (int j = 0; j < 4; j++) {
            u16 v = qs[(t * 4 + j) * 2];
            u32 e = (v >> 7) & 0xFF;
            c += (e >= 100 && e <= 134) ? 1 : 0;
        }
#pragma unroll
        for (int off = 32; off > 0; off >>= 1) c += __shfl_down(c, off, 64);
        if (t == 0) s_isf = (c < 128) ? 1u : 0u;
    }
    __syncthreads();
    const u32 isf32 = s_isf;

    if (b == 0) {
        // biases + dummy -> bf16
#pragma unroll
        for (int j = 0; j < 4; j++) {
            int i = t + j * 512;
            if (i < 1792) {
                float v;
                if (i < 256)       v = ldf(dummy, i, isf32);
                else if (i < 768)  v = ldf(b1, i - 256, isf32);
                else if (i < 1280) v = ldf(b2, i - 768, isf32);
                else               v = ldf(b3, i - 1280, isf32);
                ws[WS_DUM + i] = f2bf(v);
            }
        }
        // adjacency
        __shared__ float A[4096];
        __shared__ float deg[64];
        __shared__ float dinv[64];
        __shared__ int er[N_EDGES];
        __shared__ int ec[N_EDGES];
        __shared__ float ewf[N_EDGES];
        if (t < N_EDGES) {
            er[t] = eidx[t];
            ec[t] = eidx[N_EDGES + t];
            ewf[t] = ldf(ew, t, isf32);
        }
        if (t < 64) deg[t] = 1.0f;   // self-loop weight
        for (int i = t; i < 4096; i += 512) A[i] = 0.f;
        __syncthreads();
        if (t < N_EDGES) atomicAdd(&deg[ec[t]], ewf[t]);
        __syncthreads();
        if (t < 64) dinv[t] = 1.0f / sqrtf(deg[t]);
        __syncthreads();
        if (t < N_EDGES) atomicAdd(&A[ec[t] * 64 + er[t]], dinv[er[t]] * ewf[t] * dinv[ec[t]]);
        __syncthreads();
        if (t < 64) A[t * 64 + t] += dinv[t] * dinv[t];
        __syncthreads();
        // A-pack: elem (k>>3)*512 + m*8 + (k&7) = A[m][k]
        for (int i = t; i < 4096; i += 512) {
            int chunk = i >> 9, m = (i >> 3) & 63, j = i & 7;
            ws[WS_ADJA + i] = f2bf(A[m * 64 + chunk * 8 + j]);
        }
        // B-pack of A^T: chunk = ntc*2+kk: lane l, j: A[c][k], k=kk*32+(l>>4)*8+j, c=ntc*16+(l&15)
        for (int i = t; i < 4096; i += 512) {
            int chunk = i >> 9, l = (i >> 3) & 63, j = i & 7;
            int ntc = chunk >> 1, kk = chunk & 1;
            int k = kk * 32 + (l >> 4) * 8 + j;
            int c2 = ntc * 16 + (l & 15);
            ws[WS_ADJB + i] = f2bf(A[c2 * 64 + k]);
        }
        if (t == 0) *(u32*)(ws + WS_FLAG) = isf32;
    } else {
        const int bw = (b - 1) * 8 + (t >> 6);
        const int tl = t & 63;
        const void* src;
        int N, K32, dst, nt, kk;
        if (bw < 256)      { src = W1; N = 512; K32 = 8;  dst = WS_W1; nt = bw / 8;          kk = bw % 8; }
        else if (bw < 768) { src = W2; N = 512; K32 = 16; dst = WS_W2; nt = (bw - 256) / 16; kk = (bw - 256) % 16; }
        else               { src = W3; N = 256; K32 = 16; dst = WS_W3; nt = (bw - 768) / 16; kk = (bw - 768) % 16; }
        const int col = nt * 16 + (tl & 15);
        const int krow = kk * 32 + (tl >> 4) * 8;
        u16 v[8];
#pragma unroll
        for (int j = 0; j < 8; j++) v[j] = f2bf(ldf(src, (krow + j) * N + col, isf32));
        u16* o = ws + dst + (nt * K32 + kk) * 512 + tl * 8;
#pragma unroll
        for (int j = 0; j < 8; j++) o[j] = v[j];
    }
}

// ---------------------------------------------------------------------------
// fused: pool (bucket-gather, no atomic-max) + 3 GCN layers, one block per
// batch elem, 1024 threads = 16 waves, LDS 148 KB -> 1 block/CU, 4 waves/SIMD.
// ---------------------------------------------------------------------------
__global__ __launch_bounds__(1024, 4) void fused(
    const int* __restrict__ allocs, const void* __restrict__ qembs,
    const u16* __restrict__ wsr, void* __restrict__ out) {

    __shared__ __align__(16) u16 BH1[32768];   // 64KB: h1 A-pack; later hw3 B-pack (first 32KB)
    __shared__ __align__(16) u16 BH2[32768];   // 64KB: X A-pack (first 32KB); later h2 A-pack
    __shared__ __align__(16) u16 SCR[10240];   // 20KB: pool bookkeeping, then per-wave transpose scratch

    const int t = threadIdx.x, bb = blockIdx.x;
    const int wave = t >> 6, lane = t & 63, quad = lane >> 4, nl = lane & 15;
    const u32 isf32 = *(const u32*)(wsr + WS_FLAG);

    // ================= pooling: counting-sort buckets + wave gather =================
    {
        int* AL   = (int*)SCR;          // [1024]
        int* LIST = (int*)SCR + 1024;   // [1024]
        int* CNT  = (int*)SCR + 2048;   // [64]
        int* SST  = (int*)SCR + 2112;   // [64]
        int* WOF  = (int*)SCR + 2176;   // [64]
        if (t < 64) CNT[t] = 0;
        __syncthreads();
        const int myc = allocs[bb * 1024 + t];
        AL[t] = myc;
        atomicAdd(&CNT[myc], 1);
        __syncthreads();
        if (t < 64) {
            int v = CNT[t], s = v;
#pragma unroll
            for (int off = 1; off < 64; off <<= 1) {
                int u = __shfl_up(s, off, 64);
                if (t >= off) s += u;
            }
            SST[t] = s - v;
            WOF[t] = s - v;
        }
        __syncthreads();
        {
            int pos = atomicAdd(&WOF[myc], 1);
            LIST[pos] = t;
        }
        __syncthreads();
        // gather: wave w owns cores w*4..w*4+3; lane owns dims lane*4..+3
        float dums[4];
#pragma unroll
        for (int jj = 0; jj < 4; jj++) dums[jj] = bf2f(wsr[WS_DUM + lane * 4 + jj]);
        for (int i = 0; i < 4; i++) {
            const int c = wave * 4 + i;
            const int L = CNT[c], S = SST[c];
            float vm0 = -3.4e38f, vm1 = -3.4e38f, vm2 = -3.4e38f, vm3 = -3.4e38f;
            if (isf32) {
                const float4* qb = (const float4*)qembs;
                for (int j = 0; j < L; j++) {
                    int q = LIST[S + j];
                    float4 v = qb[q * 64 + lane];
                    vm0 = fmaxf(vm0, v.x); vm1 = fmaxf(vm1, v.y);
                    vm2 = fmaxf(vm2, v.z); vm3 = fmaxf(vm3, v.w);
                }
            } else {
                const uint2* qb = (const uint2*)qembs;
                for (int j = 0; j < L; j++) {
                    int q = LIST[S + j];
                    uint2 r = qb[q * 64 + lane];
                    vm0 = fmaxf(vm0, bf2f((u16)(r.x & 0xffff)));
                    vm1 = fmaxf(vm1, bf2f((u16)(r.x >> 16)));
                    vm2 = fmaxf(vm2, bf2f((u16)(r.y & 0xffff)));
                    vm3 = fmaxf(vm3, bf2f((u16)(r.y >> 16)));
                }
            }
            short4v p;
            p[0] = (short)f2bf(fmaxf(vm0, dums[0]));
            p[1] = (short)f2bf(fmaxf(vm1, dums[1]));
            p[2] = (short)f2bf(fmaxf(vm2, dums[2]));
            p[3] = (short)f2bf(fmaxf(vm3, dums[3]));
            // X A-pack into BH2: k=d=lane*4+jj -> (d>>3)*512 + c*8 + (d&7)
            *(short4v*)(BH2 + (lane >> 1) * 512 + c * 8 + (lane & 1) * 4) = p;
        }
    }
    __syncthreads();

    u16* scr = SCR + wave * 640;

    // mm1 (h @ W, 2 stripes/wave) + fused agg vs A^T; relu+bias; A-pack out.
    auto layerT = [&](auto K32c, const u16* __restrict__ W, const u16* __restrict__ bias,
                      const u16* __restrict__ Hin, u16* __restrict__ Hout) {
        constexpr int K32 = decltype(K32c)::value;
        const int s0 = wave * 2;
        f32x4 acc[2][4];
#pragma unroll
        for (int s = 0; s < 2; s++)
#pragma unroll
            for (int rt = 0; rt < 4; rt++) acc[s][rt] = f32x4{0.f, 0.f, 0.f, 0.f};
#pragma unroll
        for (int kk = 0; kk < K32; kk++) {
            short8 a[4], bch[2];
#pragma unroll
            for (int rt = 0; rt < 4; rt++)
                a[rt] = *(const short8*)(Hin + (kk * 4 + quad) * 512 + (rt * 16 + nl) * 8);
#pragma unroll
            for (int s = 0; s < 2; s++)
                bch[s] = *(const short8*)(W + ((s0 + s) * K32 + kk) * 512 + lane * 8);
#pragma unroll
            for (int s = 0; s < 2; s++)
#pragma unroll
                for (int rt = 0; rt < 4; rt++)
                    acc[s][rt] = __builtin_amdgcn_mfma_f32_16x16x32_bf16(a[rt], bch[s], acc[s][rt], 0, 0, 0);
        }
#pragma unroll
        for (int s = 0; s < 2; s++) {
            const int nt = s0 + s;
            f32x4 agg[4];
#pragma unroll
            for (int ntc = 0; ntc < 4; ntc++) agg[ntc] = f32x4{0.f, 0.f, 0.f, 0.f};
#pragma unroll
            for (int h = 0; h < 2; h++) {
#pragma unroll
                for (int r2 = 0; r2 < 2; r2++) {
                    f32x4 v = acc[s][2 * h + r2];
                    short4v p;
#pragma unroll
                    for (int rr = 0; rr < 4; rr++) p[rr] = (short)f2bf(v[rr]);
                    *(short4v*)(scr + nl * 40 + r2 * 16 + quad * 4) = p;
                }
                short8 hwf = *(const short8*)(scr + nl * 40 + quad * 8);
#pragma unroll
                for (int ntc = 0; ntc < 4; ntc++) {
                    short8 adjB = *(const short8*)(wsr + WS_ADJB + (ntc * 2 + h) * 512 + lane * 8);
                    agg[ntc] = __builtin_amdgcn_mfma_f32_16x16x32_bf16(hwf, adjB, agg[ntc], 0, 0, 0);
                }
            }
            float bv[4];
#pragma unroll
            for (int rr = 0; rr < 4; rr++) bv[rr] = bf2f(bias[nt * 16 + quad * 4 + rr]);
#pragma unroll
            for (int ntc = 0; ntc < 4; ntc++) {
                short4v p;
#pragma unroll
                for (int rr = 0; rr < 4; rr++)
                    p[rr] = (short)f2bf(fmaxf(agg[ntc][rr] + bv[rr], 0.f));
                *(short4v*)(Hout + (nt * 2 + (quad >> 1)) * 512 + (ntc * 16 + nl) * 8 + (quad & 1) * 4) = p;
            }
        }
    };

    // L3 mm1: hw3 = h2 @ W3 (N=256, 1 stripe/wave); B-pack into BH1[0:16K]
    auto layer3 = [&](const u16* __restrict__ W) {
        const int nt = wave;
        f32x4 acc[4];
#pragma unroll
        for (int rt = 0; rt < 4; rt++) acc[rt] = f32x4{0.f, 0.f, 0.f, 0.f};
#pragma unroll
        for (int kk = 0; kk < 16; kk++) {
            short8 a[4];
#pragma unroll
            for (int rt = 0; rt < 4; rt++)
                a[rt] = *(const short8*)(BH2 + (kk * 4 + quad) * 512 + (rt * 16 + nl) * 8);
            short8 bch = *(const short8*)(W + (nt * 16 + kk) * 512 + lane * 8);
#pragma unroll
            for (int rt = 0; rt < 4; rt++)
                acc[rt] = __builtin_amdgcn_mfma_f32_16x16x32_bf16(a[rt], bch, acc[rt], 0, 0, 0);
        }
#pragma unroll
        for (int h = 0; h < 2; h++) {
#pragma unroll
            for (int r2 = 0; r2 < 2; r2++) {
                f32x4 v = acc[2 * h + r2];
                short4v p;
#pragma unroll
                for (int rr = 0; rr < 4; rr++) p[rr] = (short)f2bf(v[rr]);
                *(short4v*)(scr + nl * 40 + r2 * 16 + quad * 4) = p;
            }
            short8 hwf = *(const short8*)(scr + nl * 40 + quad * 8);
            *(short8*)(BH1 + (nt * 2 + h) * 512 + lane * 8) = hwf;
        }
    };

    // final: out = relu(A_norm @ hw3 + b3)
    auto finalOut = [&]() {
        const int rt2 = wave & 3, nt0 = (wave >> 2) * 4;
        short8 aA[2];
#pragma unroll
        for (int h = 0; h < 2; h++)
            aA[h] = *(const short8*)(wsr + WS_ADJA + (h * 4 + quad) * 512 + (rt2 * 16 + nl) * 8);
        float* outf = (float*)out + (size_t)bb * 16384;
        u16* outu = (u16*)out + (size_t)bb * 16384;
#pragma unroll
        for (int ni = 0; ni < 4; ni++) {
            const int nt = nt0 + ni;
            short8 b0 = *(const short8*)(BH1 + (nt * 2 + 0) * 512 + lane * 8);
            short8 b1 = *(const short8*)(BH1 + (nt * 2 + 1) * 512 + lane * 8);
            f32x4 acc = f32x4{0.f, 0.f, 0.f, 0.f};
            acc = __builtin_amdgcn_mfma_f32_16x16x32_bf16(aA[0], b0, acc, 0, 0, 0);
            acc = __builtin_amdgcn_mfma_f32_16x16x32_bf16(aA[1], b1, acc, 0, 0, 0);
            const int n = nt * 16 + nl;
            const float bv = bf2f(wsr[WS_B3 + n]);
#pragma unroll
            for (int rr = 0; rr < 4; rr++) {
                const int m2 = rt2 * 16 + quad * 4 + rr;
                float val = fmaxf(acc[rr] + bv, 0.f);
                if (isf32) outf[m2 * 256 + n] = val;
                else       outu[m2 * 256 + n] = f2bf(val);
            }
        }
    };

    layerT(std::integral_constant<int, 8>{},  wsr + WS_W1, wsr + WS_B1, BH2, BH1);
    __syncthreads();
    layerT(std::integral_constant<int, 16>{}, wsr + WS_W2, wsr + WS_B2, BH1, BH2);
    __syncthreads();
    layer3(wsr + WS_W3);
    __syncthreads();
    finalOut();
}

// ---------------------------------------------------------------------------
extern "C" void kernel_launch(void* const* d_in, const int* in_sizes, int n_in,
                              void* d_out, int out_size, void* d_ws, size_t ws_size,
                              hipStream_t stream) {
    const int* allocs = (const int*)d_in[0];
    const void* qembs = d_in[1];
    const void* dummy = d_in[2];
    const int* eidx   = (const int*)d_in[3];
    const void* ew    = d_in[4];
    const void* W1 = d_in[5];
    const void* b1 = d_in[6];
    const void* W2 = d_in[7];
    const void* b2 = d_in[8];
    const void* W3 = d_in[9];
    const void* b3 = d_in[10];
    u16* ws = (u16*)d_ws;

    prep<<<129, 512, 0, stream>>>(eidx, ew, qembs, dummy, W1, b1, W2, b2, W3, b3, ws);
    fused<<<512, 1024, 0, stream>>>(allocs, qembs, ws, d_out);
}